// Round 1
// baseline (1922.686 us; speedup 1.0000x reference)
//
#include <hip/hip_runtime.h>

#define NN 50000
#define EE 100000
#define FF 64
#define HH 128
#define HEADS 4
#define BB 64
#define SS 512
#define LCC 8

#define TM 64
#define TN 64
#define TKK 16

// ---------------- generic fp32 GEMM: C = act(A[M,K] @ W[K,*] + bias) ----------------
// A row-major, lda == K. W row-major with row stride ldw (pointer pre-offset to the
// desired column window). C row stride ldc (pointer pre-offset). Nout == gridDim.x*64.
__global__ __launch_bounds__(256) void gemm_bias_act(
    const float* __restrict__ A, const float* __restrict__ W,
    const float* __restrict__ bias, float* __restrict__ C,
    int M, int K, int ldw, int ldc, int act)
{
    __shared__ float As[TKK][TM];   // transposed A tile
    __shared__ float Bs[TKK][TN];
    const int t  = threadIdx.x;
    const int n0 = blockIdx.x * TN;
    const int m0 = blockIdx.y * TM;
    const int tx = t & 15, ty = t >> 4;
    const int arow = t >> 2, acol = (t & 3) << 2;

    float acc[4][4] = {};

    for (int k0 = 0; k0 < K; k0 += TKK) {
        float4 av = make_float4(0.f, 0.f, 0.f, 0.f);
        const int gm = m0 + arow;
        if (gm < M)
            av = *reinterpret_cast<const float4*>(A + (size_t)gm * K + k0 + acol);
        As[acol + 0][arow] = av.x;
        As[acol + 1][arow] = av.y;
        As[acol + 2][arow] = av.z;
        As[acol + 3][arow] = av.w;

        float4 bv = *reinterpret_cast<const float4*>(W + (size_t)(k0 + ty) * ldw + n0 + (tx << 2));
        *reinterpret_cast<float4*>(&Bs[ty][tx << 2]) = bv;

        __syncthreads();
#pragma unroll
        for (int kk = 0; kk < TKK; ++kk) {
            float4 a4 = *reinterpret_cast<const float4*>(&As[kk][ty << 2]);
            float4 b4 = *reinterpret_cast<const float4*>(&Bs[kk][tx << 2]);
            float a[4] = {a4.x, a4.y, a4.z, a4.w};
            float b[4] = {b4.x, b4.y, b4.z, b4.w};
#pragma unroll
            for (int i = 0; i < 4; ++i)
#pragma unroll
                for (int j = 0; j < 4; ++j)
                    acc[i][j] += a[i] * b[j];
        }
        __syncthreads();
    }

    float bj[4];
#pragma unroll
    for (int j = 0; j < 4; ++j) bj[j] = bias[n0 + (tx << 2) + j];

#pragma unroll
    for (int i = 0; i < 4; ++i) {
        const int gm = m0 + (ty << 2) + i;
        if (gm < M) {
            float* crow = C + (size_t)gm * ldc + n0 + (tx << 2);
#pragma unroll
            for (int j = 0; j < 4; ++j) {
                float v = acc[i][j] + bj[j];
                if (act) v = fmaxf(v, 0.f);
                crow[j] = v;
            }
        }
    }
}

// ---------------- helpers ----------------
__device__ __forceinline__ unsigned encf(float f) {
    unsigned u = __float_as_uint(f);
    return (u & 0x80000000u) ? ~u : (u | 0x80000000u);
}
__device__ __forceinline__ float decf(unsigned u) {
    u = (u & 0x80000000u) ? (u & 0x7fffffffu) : ~u;
    return __uint_as_float(u);
}

__global__ void fill_kernel(unsigned* __restrict__ p, unsigned v, int n) {
    int i = blockIdx.x * blockDim.x + threadIdx.x;
    if (i < n) p[i] = v;
}

__global__ void relu_kernel(float* __restrict__ p, long long n) {
    long long i = (long long)blockIdx.x * blockDim.x + threadIdx.x;
    if (i < n) p[i] = fmaxf(p[i], 0.f);
}

// one wave per edge: score = (q[dst] . k[src]) * scale ; atomicMax into per-dst max
__global__ void edge_scores_kernel(
    const float* __restrict__ q, const float* __restrict__ k,
    const int* __restrict__ src, const int* __restrict__ dst,
    float* __restrict__ scores, unsigned* __restrict__ menc, float scale, int E)
{
    int e = blockIdx.x * (blockDim.x >> 6) + (threadIdx.x >> 6);
    int lane = threadIdx.x & 63;
    if (e >= E) return;
    int s = src[e], d = dst[e];
    const float* qr = q + (size_t)d * HH;
    const float* kr = k + (size_t)s * HH;
    float acc = qr[lane] * kr[lane] + qr[lane + 64] * kr[lane + 64];
#pragma unroll
    for (int off = 32; off > 0; off >>= 1) acc += __shfl_down(acc, off, 64);
    if (lane == 0) {
        float sc = acc * scale;
        scores[e] = sc;
        atomicMax(&menc[d], encf(sc));
    }
}

__global__ void edge_expsum_kernel(
    float* __restrict__ scores, const unsigned* __restrict__ menc,
    float* __restrict__ denom, const int* __restrict__ dst, int E)
{
    int e = blockIdx.x * blockDim.x + threadIdx.x;
    if (e >= E) return;
    int d = dst[e];
    float m = decf(menc[d]);
    float s = __expf(scores[e] - m);
    scores[e] = s;
    atomicAdd(&denom[d], s);
}

// one wave per edge: C[dst, :] += alpha * v[src, :]
__global__ void edge_scatter_kernel(
    const float* __restrict__ scores, const float* __restrict__ denom,
    const float* __restrict__ v, const int* __restrict__ src,
    const int* __restrict__ dst, float* __restrict__ C, int ldc, int E)
{
    int e = blockIdx.x * (blockDim.x >> 6) + (threadIdx.x >> 6);
    int lane = threadIdx.x & 63;
    if (e >= E) return;
    int s = src[e], d = dst[e];
    float alpha = scores[e] / (denom[d] + 1e-16f);
    const float* vr = v + (size_t)s * HH;
    float* cr = C + (size_t)d * ldc;
    atomicAdd(&cr[lane], alpha * vr[lane]);
    atomicAdd(&cr[lane + 64], alpha * vr[lane + 64]);
}

// one wave per node: gsum[batch[n], :] += h[n, :] ; cnt[batch[n]] += 1
__global__ void pool_kernel(
    const float* __restrict__ h, const int* __restrict__ batch,
    float* __restrict__ gsum, float* __restrict__ cnt, int n)
{
    int node = blockIdx.x * (blockDim.x >> 6) + (threadIdx.x >> 6);
    int lane = threadIdx.x & 63;
    if (node >= n) return;
    int b = batch[node];
    const float* hr = h + (size_t)node * HH;
    atomicAdd(&gsum[b * HH + lane], hr[lane]);
    atomicAdd(&gsum[b * HH + lane + 64], hr[lane + 64]);
    if (lane == 0) atomicAdd(&cnt[b], 1.0f);
}

__global__ void pool_fin_kernel(const float* __restrict__ gsum,
                                const float* __restrict__ cnt, float* __restrict__ g)
{
    int i = blockIdx.x * blockDim.x + threadIdx.x;
    if (i < BB * HH) g[i] = gsum[i] / fmaxf(cnt[i / HH], 1.0f);
}

// out = concat over 7 heads of g @ W_s + b_s  (one thread per output element)
__global__ void out_heads_kernel(
    const float* __restrict__ g,
    const float* __restrict__ w0, const float* __restrict__ b0,
    const float* __restrict__ w1, const float* __restrict__ b1,
    const float* __restrict__ w2, const float* __restrict__ b2,
    const float* __restrict__ w3, const float* __restrict__ b3,
    const float* __restrict__ w4, const float* __restrict__ b4,
    const float* __restrict__ w5, const float* __restrict__ b5,
    const float* __restrict__ w6, const float* __restrict__ b6,
    float* __restrict__ out, int total)
{
    int t = blockIdx.x * blockDim.x + threadIdx.x;
    if (t >= total) return;
    const float* W; const float* bias; int cols; int local;
    if      (t < 64)    { W = w0; bias = b0; cols = 1;   local = t; }
    else if (t < 320)   { W = w1; bias = b1; cols = 4;   local = t - 64; }
    else if (t < 512)   { W = w2; bias = b2; cols = 3;   local = t - 320; }
    else if (t < 33280) { W = w3; bias = b3; cols = SS;  local = t - 512; }
    else if (t < 66048) { W = w4; bias = b4; cols = SS;  local = t - 33280; }
    else if (t < 98816) { W = w5; bias = b5; cols = SS;  local = t - 66048; }
    else                { W = w6; bias = b6; cols = LCC; local = t - 98816; }
    int b = local / cols, c = local % cols;
    const float* gr = g + b * HH;
    float acc = bias[c];
#pragma unroll 8
    for (int i = 0; i < HH; ++i) acc += gr[i] * W[i * cols + c];
    out[t] = acc;
}

// ---------------- orchestration ----------------
extern "C" void kernel_launch(void* const* d_in, const int* in_sizes, int n_in,
                              void* d_out, int out_size, void* d_ws, size_t ws_size,
                              hipStream_t stream)
{
    (void)in_sizes; (void)n_in; (void)out_size; (void)ws_size;

    const float* nf   = (const float*)d_in[0];
    const int*   ei   = (const int*)d_in[1];
    const int*   src  = ei;
    const int*   dst  = ei + EE;
    const int*   batch= (const int*)d_in[2];
    const float* Wp   = (const float*)d_in[3];
    const float* bp   = (const float*)d_in[4];
    const float* Wq1  = (const float*)d_in[5];
    const float* bq1  = (const float*)d_in[6];
    const float* Wk1  = (const float*)d_in[7];
    const float* bk1  = (const float*)d_in[8];
    const float* Wv1  = (const float*)d_in[9];
    const float* bv1  = (const float*)d_in[10];
    const float* Ws1  = (const float*)d_in[11];
    const float* bs1  = (const float*)d_in[12];
    const float* Wq2  = (const float*)d_in[13];
    const float* bq2  = (const float*)d_in[14];
    const float* Wk2  = (const float*)d_in[15];
    const float* bk2  = (const float*)d_in[16];
    const float* Wv2  = (const float*)d_in[17];
    const float* bv2  = (const float*)d_in[18];
    const float* Ws2  = (const float*)d_in[19];
    const float* bs2  = (const float*)d_in[20];
    const float* crW  = (const float*)d_in[21];
    const float* crb  = (const float*)d_in[22];
    const float* hlW  = (const float*)d_in[23];
    const float* hlb  = (const float*)d_in[24];
    const float* mtW  = (const float*)d_in[25];
    const float* mtb  = (const float*)d_in[26];
    const float* p1W  = (const float*)d_in[27];
    const float* p1b  = (const float*)d_in[28];
    const float* p2W  = (const float*)d_in[29];
    const float* p2b  = (const float*)d_in[30];
    const float* dtW  = (const float*)d_in[31];
    const float* dtb  = (const float*)d_in[32];
    const float* slW  = (const float*)d_in[33];
    const float* slb  = (const float*)d_in[34];
    float* out = (float*)d_out;

    // workspace layout (~231 MB)
    float*    h0     = (float*)d_ws;                     // N*128
    float*    h1     = h0 + (size_t)NN * HH;             // N*512
    float*    h2     = h1 + (size_t)NN * 4 * HH;         // N*128
    float*    qb     = h2 + (size_t)NN * HH;             // N*128
    float*    kb     = qb + (size_t)NN * HH;             // N*128
    float*    vb     = kb + (size_t)NN * HH;             // N*128
    float*    scores = vb + (size_t)NN * HH;             // E
    unsigned* menc   = (unsigned*)(scores + EE);         // N
    float*    denom  = (float*)(menc + NN);              // N
    float*    gsum   = denom + NN;                       // B*128
    float*    cntf   = gsum + BB * HH;                   // B
    float*    gbuf   = cntf + BB;                        // B*128

    const float scale = 0.08838834764831845f; // 1/sqrt(128)
    const dim3 blk(256);
    const int mgrid = (NN + TM - 1) / TM;  // 782

    // h0 = relu(nf @ Wp + bp)
    gemm_bias_act<<<dim3(HH / TN, mgrid), blk, 0, stream>>>(nf, Wp, bp, h0, NN, FF, HH, HH, 1);
    // h1 = h0 @ Ws1 + bs1  (skip; attention accumulates on top)
    gemm_bias_act<<<dim3(4 * HH / TN, mgrid), blk, 0, stream>>>(h0, Ws1, bs1, h1, NN, HH, 4 * HH, 4 * HH, 0);

    for (int h = 0; h < HEADS; ++h) {
        gemm_bias_act<<<dim3(HH / TN, mgrid), blk, 0, stream>>>(h0, Wq1 + h * HH, bq1 + h * HH, qb, NN, HH, 4 * HH, HH, 0);
        gemm_bias_act<<<dim3(HH / TN, mgrid), blk, 0, stream>>>(h0, Wk1 + h * HH, bk1 + h * HH, kb, NN, HH, 4 * HH, HH, 0);
        gemm_bias_act<<<dim3(HH / TN, mgrid), blk, 0, stream>>>(h0, Wv1 + h * HH, bv1 + h * HH, vb, NN, HH, 4 * HH, HH, 0);
        fill_kernel<<<(NN + 255) / 256, blk, 0, stream>>>(menc, 0u, NN);
        fill_kernel<<<(NN + 255) / 256, blk, 0, stream>>>((unsigned*)denom, 0u, NN);
        edge_scores_kernel<<<(EE + 3) / 4, blk, 0, stream>>>(qb, kb, src, dst, scores, menc, scale, EE);
        edge_expsum_kernel<<<(EE + 255) / 256, blk, 0, stream>>>(scores, menc, denom, dst, EE);
        edge_scatter_kernel<<<(EE + 3) / 4, blk, 0, stream>>>(scores, denom, vb, src, dst, h1 + h * HH, 4 * HH, EE);
    }
    relu_kernel<<<(int)(((long long)NN * 4 * HH + 255) / 256), blk, 0, stream>>>(h1, (long long)NN * 4 * HH);

    // conv2 (heads=1, in 512, out 128)
    gemm_bias_act<<<dim3(HH / TN, mgrid), blk, 0, stream>>>(h1, Ws2, bs2, h2, NN, 4 * HH, HH, HH, 0);
    gemm_bias_act<<<dim3(HH / TN, mgrid), blk, 0, stream>>>(h1, Wq2, bq2, qb, NN, 4 * HH, HH, HH, 0);
    gemm_bias_act<<<dim3(HH / TN, mgrid), blk, 0, stream>>>(h1, Wk2, bk2, kb, NN, 4 * HH, HH, HH, 0);
    gemm_bias_act<<<dim3(HH / TN, mgrid), blk, 0, stream>>>(h1, Wv2, bv2, vb, NN, 4 * HH, HH, HH, 0);
    fill_kernel<<<(NN + 255) / 256, blk, 0, stream>>>(menc, 0u, NN);
    fill_kernel<<<(NN + 255) / 256, blk, 0, stream>>>((unsigned*)denom, 0u, NN);
    edge_scores_kernel<<<(EE + 3) / 4, blk, 0, stream>>>(qb, kb, src, dst, scores, menc, scale, EE);
    edge_expsum_kernel<<<(EE + 255) / 256, blk, 0, stream>>>(scores, menc, denom, dst, EE);
    edge_scatter_kernel<<<(EE + 3) / 4, blk, 0, stream>>>(scores, denom, vb, src, dst, h2, HH, EE);
    relu_kernel<<<(int)(((long long)NN * HH + 255) / 256), blk, 0, stream>>>(h2, (long long)NN * HH);

    // global mean pool
    fill_kernel<<<(BB * HH + BB + 255) / 256, blk, 0, stream>>>((unsigned*)gsum, 0u, BB * HH + BB);
    pool_kernel<<<(NN + 3) / 4, blk, 0, stream>>>(h2, batch, gsum, cntf, NN);
    pool_fin_kernel<<<(BB * HH + 255) / 256, blk, 0, stream>>>(gsum, cntf, gbuf);

    // output heads (total = 64*(1+4+3+512+512+512+8) = 99328)
    const int total = BB * (1 + 4 + 3 + SS + SS + SS + LCC);
    out_heads_kernel<<<(total + 255) / 256, blk, 0, stream>>>(
        gbuf, crW, crb, hlW, hlb, mtW, mtb, p1W, p1b, p2W, p2b, dtW, dtb, slW, slb, out, total);
}

// Round 2
// 846.853 us; speedup vs baseline: 2.2704x; 2.2704x over previous
//
#include <hip/hip_runtime.h>

#define NN 50000
#define EE 100000
#define FF 64
#define HH 128
#define HEADS 4
#define BB 64
#define SS 512
#define LCC 8

// ---- bf16 helpers (bit-level, no hip_bf16 dependency) ----
__device__ __forceinline__ float b2f(ushort u) {
    return __uint_as_float(((unsigned)u) << 16);
}
__device__ __forceinline__ ushort f2b(float f) {
    unsigned u = __float_as_uint(f);
    unsigned r = (u + 0x7FFFu + ((u >> 16) & 1u)) >> 16;   // RNE
    return (ushort)r;
}

typedef __attribute__((ext_vector_type(4))) float f32x4;
typedef __attribute__((ext_vector_type(8))) short s16x8;

// ================= bf16 MFMA GEMM =================
// C[M][ldc] = act(A[M][K] @ Bt[N][K]^T + bias), A/Bt bf16, bias fp32.
// grid = (Ntot/128, ceil(M/128)), block = 256 (4 waves).
// flags: bit0 = relu, bit1 = store bf16 (else fp32)
#define BM 128
#define BN 128
#define BK 32
#define KP 40   // padded K stride in LDS (bf16 elems): 80B rows -> 2-way bank aliasing (free)

__global__ __launch_bounds__(256) void gemm_bf16(
    const ushort* __restrict__ A, const ushort* __restrict__ Bt,
    const float* __restrict__ bias, void* __restrict__ Cout,
    int M, int K, int ldc, int flags)
{
    __shared__ ushort As[BM * KP];
    __shared__ ushort Bs[BN * KP];
    const int t = threadIdx.x;
    const int m0 = blockIdx.y * BM;
    const int n0 = blockIdx.x * BN;
    const int lane = t & 63;
    const int wave = t >> 6;
    const int wm = (wave & 1) * 64;
    const int wn = (wave >> 1) * 64;
    const int lrow = lane & 15;
    const int lk8  = (lane >> 4) * 8;

    f32x4 acc[4][4] = {};

    const int srow = t >> 1;          // 0..127
    const int soff = (t & 1) * 16;    // 0 / 16 (bf16 elems)

    for (int k0 = 0; k0 < K; k0 += BK) {
        // stage A tile (128 x 32), guarded on M
        {
            const int gm = m0 + srow;
            float4 v0 = make_float4(0.f, 0.f, 0.f, 0.f);
            float4 v1 = make_float4(0.f, 0.f, 0.f, 0.f);
            if (gm < M) {
                const float4* p = (const float4*)(A + (size_t)gm * K + k0 + soff);
                v0 = p[0]; v1 = p[1];
            }
            float4* d = (float4*)&As[srow * KP + soff];
            d[0] = v0; d[1] = v1;
        }
        // stage B tile (128 x 32) from pre-transposed weights [N][K]
        {
            const float4* p = (const float4*)(Bt + (size_t)(n0 + srow) * K + k0 + soff);
            float4 v0 = p[0];
            float4 v1 = p[1];
            float4* d = (float4*)&Bs[srow * KP + soff];
            d[0] = v0; d[1] = v1;
        }
        __syncthreads();

        s16x8 af[4], bf[4];
#pragma unroll
        for (int i = 0; i < 4; ++i)
            af[i] = *(const s16x8*)&As[(wm + i * 16 + lrow) * KP + lk8];
#pragma unroll
        for (int j = 0; j < 4; ++j)
            bf[j] = *(const s16x8*)&Bs[(wn + j * 16 + lrow) * KP + lk8];
#pragma unroll
        for (int i = 0; i < 4; ++i)
#pragma unroll
            for (int j = 0; j < 4; ++j)
                acc[i][j] = __builtin_amdgcn_mfma_f32_16x16x32_bf16(af[i], bf[j], acc[i][j], 0, 0, 0);
        __syncthreads();
    }

    // epilogue: C[row = m0+wm+i*16+(lane>>4)*4+r][col = n0+wn+j*16+(lane&15)]
    const int rbase = (lane >> 4) * 4;
#pragma unroll
    for (int i = 0; i < 4; ++i) {
#pragma unroll
        for (int r = 0; r < 4; ++r) {
            const int gm = m0 + wm + i * 16 + rbase + r;
            if (gm < M) {
                const size_t rowoff = (size_t)gm * ldc;
#pragma unroll
                for (int j = 0; j < 4; ++j) {
                    const int gn = n0 + wn + j * 16 + lrow;
                    float v = acc[i][j][r] + bias[gn];
                    if (flags & 1) v = fmaxf(v, 0.f);
                    if (flags & 2) ((ushort*)Cout)[rowoff + gn] = f2b(v);
                    else           ((float*)Cout)[rowoff + gn] = v;
                }
            }
        }
    }
}

// ================= weight prep: transpose + bf16 + per-head q|k|v gather =================
#define W1OFF  8192     // after Wpt [128][64]
#define WS1OFF 204800   // 8192 + 4*49152   (4 heads of [384][128])
#define W2OFF  270336   // + 65536          (Ws1t [512][128])
#define WS2OFF 466944   // + 196608         (conv2 qkv [384][512])
#define WTOTAL 532480   // + 65536          (Ws2t [128][512])
#define BTOTAL 1920     // conv1 4*384 + conv2 384 gathered biases

__global__ void wprep_kernel(
    const float* __restrict__ Wp,
    const float* __restrict__ Wq1, const float* __restrict__ Wk1,
    const float* __restrict__ Wv1, const float* __restrict__ Ws1,
    const float* __restrict__ Wq2, const float* __restrict__ Wk2,
    const float* __restrict__ Wv2, const float* __restrict__ Ws2,
    const float* __restrict__ bq1, const float* __restrict__ bk1, const float* __restrict__ bv1,
    const float* __restrict__ bq2, const float* __restrict__ bk2, const float* __restrict__ bv2,
    ushort* __restrict__ wt, float* __restrict__ bb)
{
    int t = blockIdx.x * 256 + threadIdx.x;
    if (t < WTOTAL) {
        float v;
        if (t < W1OFF) {                              // Wpt[n][k] = Wp[k][n], (64,128)
            int n = t >> 6, k = t & 63;
            v = Wp[k * 128 + n];
        } else if (t < WS1OFF) {                      // head h: rows [q(128)|k(128)|v(128)] x K=128
            int u = t - W1OFF;
            int h = u / 49152; u -= h * 49152;
            int r = u >> 7, k = u & 127;
            const float* W = (r < 128) ? Wq1 : (r < 256) ? Wk1 : Wv1;
            v = W[k * 512 + h * 128 + (r & 127)];
        } else if (t < W2OFF) {                       // Ws1t[n][k] = Ws1[k][n], (128,512)
            int u = t - WS1OFF;
            int n = u >> 7, k = u & 127;
            v = Ws1[k * 512 + n];
        } else if (t < WS2OFF) {                      // conv2 rows [q|k|v](384) x K=512
            int u = t - W2OFF;
            int r = u >> 9, k = u & 511;
            const float* W = (r < 128) ? Wq2 : (r < 256) ? Wk2 : Wv2;
            v = W[k * 128 + (r & 127)];
        } else {                                      // Ws2t[n][k] = Ws2[k][n], (512,128)
            int u = t - WS2OFF;
            int n = u >> 9, k = u & 511;
            v = Ws2[k * 128 + n];
        }
        wt[t] = f2b(v);
    } else if (t < WTOTAL + BTOTAL) {
        int u = t - WTOTAL;
        float v;
        if (u < 1536) {
            int h = u / 384, c = u % 384;
            const float* B = (c < 128) ? bq1 : (c < 256) ? bk1 : bv1;
            v = B[h * 128 + (c & 127)];
        } else {
            int c = u - 1536;
            const float* B = (c < 128) ? bq2 : (c < 256) ? bk2 : bv2;
            v = B[c & 127];
        }
        bb[u] = v;
    }
}

// ================= fp32 -> bf16 convert (x4 vectorized), optional relu =================
__global__ void f32_to_bf16_kernel(const float4* __restrict__ in, ushort4* __restrict__ out,
                                   int n4, int relu)
{
    int i = blockIdx.x * 256 + threadIdx.x;
    if (i >= n4) return;
    float4 v = in[i];
    if (relu) {
        v.x = fmaxf(v.x, 0.f); v.y = fmaxf(v.y, 0.f);
        v.z = fmaxf(v.z, 0.f); v.w = fmaxf(v.w, 0.f);
    }
    ushort4 o;
    o.x = f2b(v.x); o.y = f2b(v.y); o.z = f2b(v.z); o.w = f2b(v.w);
    out[i] = o;
}

// ================= misc helpers =================
__device__ __forceinline__ unsigned encf(float f) {
    unsigned u = __float_as_uint(f);
    return (u & 0x80000000u) ? ~u : (u | 0x80000000u);
}
__device__ __forceinline__ float decf(unsigned u) {
    u = (u & 0x80000000u) ? (u & 0x7fffffffu) : ~u;
    return __uint_as_float(u);
}

__global__ void fill_kernel(unsigned* __restrict__ p, unsigned v, int n) {
    int i = blockIdx.x * blockDim.x + threadIdx.x;
    if (i < n) p[i] = v;
}

// ================= edge kernels (qkv packed rows [q(128)|k(128)|v(128)], ld=384) =================
__global__ void edge_scores_kernel(
    const ushort* __restrict__ qkv, const int* __restrict__ src, const int* __restrict__ dst,
    float* __restrict__ scores, unsigned* __restrict__ menc, float scale, int ld, int E)
{
    int e = blockIdx.x * 4 + (threadIdx.x >> 6);
    int lane = threadIdx.x & 63;
    if (e >= E) return;
    int s = src[e], d = dst[e];
    const ushort* qr = qkv + (size_t)d * ld;
    const ushort* kr = qkv + (size_t)s * ld + 128;
    float acc = b2f(qr[lane]) * b2f(kr[lane]) + b2f(qr[lane + 64]) * b2f(kr[lane + 64]);
#pragma unroll
    for (int off = 32; off > 0; off >>= 1) acc += __shfl_down(acc, off, 64);
    if (lane == 0) {
        float sc = acc * scale;
        scores[e] = sc;
        atomicMax(&menc[d], encf(sc));
    }
}

__global__ void edge_expsum_kernel(
    float* __restrict__ scores, const unsigned* __restrict__ menc,
    float* __restrict__ denom, const int* __restrict__ dst, int E)
{
    int e = blockIdx.x * blockDim.x + threadIdx.x;
    if (e >= E) return;
    int d = dst[e];
    float s = __expf(scores[e] - decf(menc[d]));
    scores[e] = s;
    atomicAdd(&denom[d], s);
}

__global__ void edge_scatter_kernel(
    const float* __restrict__ scores, const float* __restrict__ denom,
    const ushort* __restrict__ qkv, const int* __restrict__ src,
    const int* __restrict__ dst, float* __restrict__ C, int ld, int ldc, int E)
{
    int e = blockIdx.x * 4 + (threadIdx.x >> 6);
    int lane = threadIdx.x & 63;
    if (e >= E) return;
    int s = src[e], d = dst[e];
    float alpha = scores[e] / (denom[d] + 1e-16f);
    const ushort* vr = qkv + (size_t)s * ld + 256;
    float* cr = C + (size_t)d * ldc;
    atomicAdd(&cr[lane],      alpha * b2f(vr[lane]));
    atomicAdd(&cr[lane + 64], alpha * b2f(vr[lane + 64]));
}

// ================= pool: run-length partial sums over sorted batch (+fused relu) =================
__global__ __launch_bounds__(256) void pool_kernel(
    const float* __restrict__ h, const int* __restrict__ batch,
    float* __restrict__ gsum, float* __restrict__ cnt, int n)
{
    int wave = threadIdx.x >> 6, lane = threadIdx.x & 63;
    int start = blockIdx.x * 256 + wave * 64;
    int end = min(start + 64, n);
    if (start >= end) return;
    int cur = batch[start];
    float a0 = 0.f, a1 = 0.f;
    int run = 0;
    for (int node = start; node < end; ++node) {
        int g = batch[node];
        if (g != cur) {
            atomicAdd(&gsum[cur * HH + lane], a0);
            atomicAdd(&gsum[cur * HH + lane + 64], a1);
            if (lane == 0) atomicAdd(&cnt[cur], (float)run);
            cur = g; a0 = a1 = 0.f; run = 0;
        }
        const float* hr = h + (size_t)node * HH;
        a0 += fmaxf(hr[lane], 0.f);
        a1 += fmaxf(hr[lane + 64], 0.f);
        ++run;
    }
    atomicAdd(&gsum[cur * HH + lane], a0);
    atomicAdd(&gsum[cur * HH + lane + 64], a1);
    if (lane == 0) atomicAdd(&cnt[cur], (float)run);
}

__global__ void pool_fin_kernel(const float* __restrict__ gsum,
                                const float* __restrict__ cnt, float* __restrict__ g)
{
    int i = blockIdx.x * blockDim.x + threadIdx.x;
    if (i < BB * HH) g[i] = gsum[i] / fmaxf(cnt[i / HH], 1.0f);
}

// ================= output heads =================
__global__ void out_heads_kernel(
    const float* __restrict__ g,
    const float* __restrict__ w0, const float* __restrict__ b0,
    const float* __restrict__ w1, const float* __restrict__ b1,
    const float* __restrict__ w2, const float* __restrict__ b2,
    const float* __restrict__ w3, const float* __restrict__ b3,
    const float* __restrict__ w4, const float* __restrict__ b4,
    const float* __restrict__ w5, const float* __restrict__ b5,
    const float* __restrict__ w6, const float* __restrict__ b6,
    float* __restrict__ out, int total)
{
    int t = blockIdx.x * blockDim.x + threadIdx.x;
    if (t >= total) return;
    const float* W; const float* bias; int cols; int local;
    if      (t < 64)    { W = w0; bias = b0; cols = 1;   local = t; }
    else if (t < 320)   { W = w1; bias = b1; cols = 4;   local = t - 64; }
    else if (t < 512)   { W = w2; bias = b2; cols = 3;   local = t - 320; }
    else if (t < 33280) { W = w3; bias = b3; cols = SS;  local = t - 512; }
    else if (t < 66048) { W = w4; bias = b4; cols = SS;  local = t - 33280; }
    else if (t < 98816) { W = w5; bias = b5; cols = SS;  local = t - 66048; }
    else                { W = w6; bias = b6; cols = LCC; local = t - 98816; }
    int b = local / cols, c = local % cols;
    const float* gr = g + b * HH;
    float acc = bias[c];
#pragma unroll 8
    for (int i = 0; i < HH; ++i) acc += gr[i] * W[i * cols + c];
    out[t] = acc;
}

// ================= orchestration =================
extern "C" void kernel_launch(void* const* d_in, const int* in_sizes, int n_in,
                              void* d_out, int out_size, void* d_ws, size_t ws_size,
                              hipStream_t stream)
{
    (void)in_sizes; (void)n_in; (void)out_size; (void)ws_size;

    const float* nf   = (const float*)d_in[0];
    const int*   ei   = (const int*)d_in[1];
    const int*   src  = ei;
    const int*   dst  = ei + EE;
    const int*   batch= (const int*)d_in[2];
    const float* Wp   = (const float*)d_in[3];
    const float* bp   = (const float*)d_in[4];
    const float* Wq1  = (const float*)d_in[5];
    const float* bq1  = (const float*)d_in[6];
    const float* Wk1  = (const float*)d_in[7];
    const float* bk1  = (const float*)d_in[8];
    const float* Wv1  = (const float*)d_in[9];
    const float* bv1  = (const float*)d_in[10];
    const float* Ws1  = (const float*)d_in[11];
    const float* bs1  = (const float*)d_in[12];
    const float* Wq2  = (const float*)d_in[13];
    const float* bq2  = (const float*)d_in[14];
    const float* Wk2  = (const float*)d_in[15];
    const float* bk2  = (const float*)d_in[16];
    const float* Wv2  = (const float*)d_in[17];
    const float* bv2  = (const float*)d_in[18];
    const float* Ws2  = (const float*)d_in[19];
    const float* bs2  = (const float*)d_in[20];
    const float* crW  = (const float*)d_in[21];
    const float* crb  = (const float*)d_in[22];
    const float* hlW  = (const float*)d_in[23];
    const float* hlb  = (const float*)d_in[24];
    const float* mtW  = (const float*)d_in[25];
    const float* mtb  = (const float*)d_in[26];
    const float* p1W  = (const float*)d_in[27];
    const float* p1b  = (const float*)d_in[28];
    const float* p2W  = (const float*)d_in[29];
    const float* p2b  = (const float*)d_in[30];
    const float* dtW  = (const float*)d_in[31];
    const float* dtb  = (const float*)d_in[32];
    const float* slW  = (const float*)d_in[33];
    const float* slb  = (const float*)d_in[34];
    float* out = (float*)d_out;

    // ---- workspace layout (~232.3 MB) ----
    float*  h1   = (float*)d_ws;                       // N*512 f32 (skip + attn accum)
    float*  h2   = h1 + (size_t)NN * 512;              // N*128 f32
    ushort* nfb  = (ushort*)h2;                        // N*64 bf16, aliases h2 (used only before h2 written)
    ushort* h0b  = (ushort*)(h2 + (size_t)NN * 128);   // N*128 bf16
    ushort* h1b  = h0b + (size_t)NN * 128;             // N*512 bf16
    ushort* qkvb = h1b + (size_t)NN * 512;             // N*384 bf16 ([q|k|v] rows)
    ushort* wt   = qkvb + (size_t)NN * 384;            // 532480 bf16 (prepped weights)
    float*  bb   = (float*)(wt + WTOTAL);              // 1920 f32 (gathered biases)
    float*  scores = bb + BTOTAL;                      // E
    unsigned* menc = (unsigned*)(scores + EE);         // N
    float*  denom  = (float*)(menc + NN);              // N  (contiguous with menc)
    float*  gsum   = denom + NN;                       // B*128
    float*  cntb   = gsum + BB * HH;                   // B   (contiguous with gsum)
    float*  gbuf   = cntb + BB;                        // B*128

    const float scale = 0.08838834764831845f; // 1/sqrt(128)
    const dim3 blk(256);
    const int mgrid = (NN + BM - 1) / BM;  // 391

    // 1) weight prep (transpose + bf16 + per-head gather)
    wprep_kernel<<<(WTOTAL + BTOTAL + 255) / 256, blk, 0, stream>>>(
        Wp, Wq1, Wk1, Wv1, Ws1, Wq2, Wk2, Wv2, Ws2,
        bq1, bk1, bv1, bq2, bk2, bv2, wt, bb);

    // 2) nf -> bf16
    f32_to_bf16_kernel<<<((NN * FF / 4) + 255) / 256, blk, 0, stream>>>(
        (const float4*)nf, (ushort4*)nfb, NN * FF / 4, 0);

    // 3) h0b = relu(nf @ Wp + bp) in bf16
    gemm_bf16<<<dim3(1, mgrid), blk, 0, stream>>>(nfb, wt, bp, h0b, NN, FF, HH, 3);

    // 4) h1 = h0 @ Ws1 + bs1 (fp32 skip base)
    gemm_bf16<<<dim3(4, mgrid), blk, 0, stream>>>(h0b, wt + W2OFF - 65536, bs1, h1, NN, HH, 4 * HH, 0);

    // 5) conv1, per head
    for (int h = 0; h < HEADS; ++h) {
        gemm_bf16<<<dim3(3, mgrid), blk, 0, stream>>>(
            h0b, wt + W1OFF + h * 49152, bb + h * 384, qkvb, NN, HH, 384, 2);
        fill_kernel<<<(2 * NN + 255) / 256, blk, 0, stream>>>(menc, 0u, 2 * NN);
        edge_scores_kernel<<<(EE + 3) / 4, blk, 0, stream>>>(qkvb, src, dst, scores, menc, scale, 384, EE);
        edge_expsum_kernel<<<(EE + 255) / 256, blk, 0, stream>>>(scores, menc, denom, dst, EE);
        edge_scatter_kernel<<<(EE + 3) / 4, blk, 0, stream>>>(scores, denom, qkvb, src, dst, h1 + h * HH, 384, 4 * HH, EE);
    }

    // 6) h1b = bf16(relu(h1))
    f32_to_bf16_kernel<<<((NN * 512 / 4) + 255) / 256, blk, 0, stream>>>(
        (const float4*)h1, (ushort4*)h1b, NN * 512 / 4, 1);

    // 7) conv2: skip base + qkv
    gemm_bf16<<<dim3(1, mgrid), blk, 0, stream>>>(h1b, wt + WS2OFF, bs2, h2, NN, 4 * HH, HH, 0);
    gemm_bf16<<<dim3(3, mgrid), blk, 0, stream>>>(h1b, wt + W2OFF, bb + 1536, qkvb, NN, 4 * HH, 384, 2);
    fill_kernel<<<(2 * NN + 255) / 256, blk, 0, stream>>>(menc, 0u, 2 * NN);
    edge_scores_kernel<<<(EE + 3) / 4, blk, 0, stream>>>(qkvb, src, dst, scores, menc, scale, 384, EE);
    edge_expsum_kernel<<<(EE + 255) / 256, blk, 0, stream>>>(scores, menc, denom, dst, EE);
    edge_scatter_kernel<<<(EE + 3) / 4, blk, 0, stream>>>(scores, denom, qkvb, src, dst, h2, 384, HH, EE);

    // 8) pool (relu fused), finalize
    fill_kernel<<<(BB * HH + BB + 255) / 256, blk, 0, stream>>>((unsigned*)gsum, 0u, BB * HH + BB);
    pool_kernel<<<(NN + 255) / 256, blk, 0, stream>>>(h2, batch, gsum, cntb, NN);
    pool_fin_kernel<<<(BB * HH + 255) / 256, blk, 0, stream>>>(gsum, cntb, gbuf);

    // 9) output heads
    const int total = BB * (1 + 4 + 3 + SS + SS + SS + LCC);
    out_heads_kernel<<<(total + 255) / 256, blk, 0, stream>>>(
        gbuf, crW, crb, hlW, hlb, mtW, mtb, p1W, p1b, p2W, p2b, dtW, dtb, slW, slb, out, total);
}